// Round 3
// baseline (66354.669 us; speedup 1.0000x reference)
//
#include <hip/hip_runtime.h>

typedef unsigned short u16;
typedef __attribute__((ext_vector_type(8))) short short8;
typedef __attribute__((ext_vector_type(4))) float f32x4;

#define NN 307      // nodes
#define NP 320      // padded nodes
#define TT 64       // time steps
#define NB 64       // batch
#define LDP 68      // ldsG row stride (f32)
#define NXP 328     // Xs (split-state) row stride in u16; 656B, 16B-aligned
#define LNEPS 1e-5f

__device__ __forceinline__ u16 f2bf(float f) {
  union { float f; unsigned u; } v; v.f = f;
  return (u16)((v.u + 0x7FFFu + ((v.u >> 16) & 1u)) >> 16);  // RNE
}
__device__ __forceinline__ float bf2f(u16 h) {
  union { unsigned u; float f; } v; v.u = ((unsigned)h) << 16;
  return v.f;
}
__device__ __forceinline__ void split3(float v, u16 &h, u16 &m, u16 &l) {
  h = f2bf(v);
  float r1 = v - bf2f(h);
  m = f2bf(r1);
  float r2 = r1 - bf2f(m);
  l = f2bf(r2);
}

#define MFMA(a, b, c) __builtin_amdgcn_mfma_f32_16x16x32_bf16((a), (b), (c), 0, 0, 0)

// ---------------------------------------------------------------------------
// prep: A -> 3x bf16 splits (zero-padded 320x320); fold Wf = W_obs @ Wg_bot.
// ---------------------------------------------------------------------------
__global__ __launch_bounds__(256) void k_prep(
    const float* __restrict__ A, const float* __restrict__ W_obs,
    const float* __restrict__ b_obs, const float* __restrict__ W_gate,
    u16* __restrict__ A_hi, u16* __restrict__ A_md, u16* __restrict__ A_lo,
    float* __restrict__ Wf, float* __restrict__ bfold)
{
  if (blockIdx.x < 400) {
    const int e = blockIdx.x * 256 + threadIdx.x;
    const int r = e / NP, c = e - r * NP;
    const float a = (r < NN && c < NN) ? A[r * NN + c] : 0.f;
    u16 h, m, l;
    split3(a, h, m, l);
    A_hi[e] = h; A_md[e] = m; A_lo[e] = l;
  } else if (threadIdx.x < 64) {
    const int dp = threadIdx.x;
    float s0 = 0.f, s1 = 0.f, s2 = 0.f, sb = 0.f;
    for (int d = 0; d < 64; ++d) {
      const float wg = W_gate[(64 + d) * 64 + dp];
      s0 += W_obs[d] * wg;
      s1 += W_obs[64 + d] * wg;
      s2 += W_obs[128 + d] * wg;
      sb += b_obs[d] * wg;
    }
    Wf[dp] = s0; Wf[64 + dp] = s1; Wf[128 + dp] = s2; bfold[dp] = sb;
  }
}

// ---------------------------------------------------------------------------
// GEMM: acc[i] (i<5, n-tiles) += X(64xK from LDS, 2-split) * A(320xK, 3-split)^T
// X rows in Xs use k-chunk XOR swizzle: element (r,k) at column k ^ ((r&3)<<3).
// Kept products: xh*ah, xh*am, xm*ah, xh*al, xm*am  (~2^-24 except X's own
// 2^-16 truncation, which the tanh/saturation path tolerates).
// ---------------------------------------------------------------------------
__device__ __forceinline__ void gemm_stage(
    const u16* __restrict__ Xs,
    const u16* __restrict__ Ah, const u16* __restrict__ Am, const u16* __restrict__ Al,
    int cr, int g, int lr, int lg, f32x4 acc[5])
{
  const int r = cr * 16 + lr;
  const int x0off = r * NXP;
  const int x1off = (64 + r) * NXP;
  const int ksw = (lg ^ (r & 3)) << 3;
  unsigned abase[5];
#pragma unroll
  for (int i = 0; i < 5; ++i) abase[i] = (unsigned)((g * 80 + i * 16 + lr) * NP);
  for (int kk = 0; kk < 10; ++kk) {
    const int kc = kk * 32 + ksw;        // swizzled LDS column
    const int ko = kk * 32 + lg * 8;     // linear global column
    const short8 xh = *(const short8*)&Xs[x0off + kc];
    const short8 xm = *(const short8*)&Xs[x1off + kc];
#pragma unroll
    for (int i = 0; i < 5; ++i) {
      const short8 ah = *(const short8*)&Ah[abase[i] + ko];
      const short8 am = *(const short8*)&Am[abase[i] + ko];
      const short8 al = *(const short8*)&Al[abase[i] + ko];
      f32x4 a = acc[i];
      a = MFMA(xh, ah, a);
      a = MFMA(xh, am, a);
      a = MFMA(xm, ah, a);
      a = MFMA(xh, al, a);
      a = MFMA(xm, am, a);
      acc[i] = a;
    }
  }
}

__device__ __forceinline__ void scatter_G(const f32x4 acc[5], float* ldsG,
                                          int cr, int g, int lr, int lg) {
  const int q = cr * 4 + lg;
#pragma unroll
  for (int i = 0; i < 5; ++i) {
    const int n = g * 80 + i * 16 + lr;
    *(f32x4*)&ldsG[n * LDP + ((q ^ (n & 15)) << 2)] = acc[i];
  }
}

// o[i][c] = sum_d ldsG[n_i][d] * ldsW[d][dq*4+c], n_i = nset + 64*i (fp32)
__device__ __forceinline__ void mat64b(const float* __restrict__ ldsG,
                                       const float* __restrict__ ldsW,
                                       int nset, int dq, float o[5][4])
{
#pragma unroll
  for (int i = 0; i < 5; ++i)
#pragma unroll
    for (int c = 0; c < 4; ++c) o[i][c] = 0.f;
  const int nq15 = nset & 15;
  for (int d4 = 0; d4 < 16; ++d4) {
    f32x4 wv[4];
#pragma unroll
    for (int m = 0; m < 4; ++m)
      wv[m] = *(const f32x4*)&ldsW[(d4 * 4 + m) * 64 + dq * 4];
#pragma unroll
    for (int i = 0; i < 5; ++i) {
      const f32x4 gr = *(const f32x4*)&ldsG[(nset + 64 * i) * LDP + ((d4 ^ nq15) << 2)];
#pragma unroll
      for (int m = 0; m < 4; ++m) {
        const float gv = gr[m];
#pragma unroll
        for (int c = 0; c < 4; ++c) o[i][c] += gv * wv[m][c];
      }
    }
  }
}

__device__ __forceinline__ void write_split2(u16* Xs, int dpp, int n, float v) {
  const u16 h = f2bf(v);
  const u16 m = f2bf(v - bf2f(h));
  const int np = n ^ ((dpp & 3) << 3);   // matches gemm read swizzle
  Xs[dpp * NXP + np] = h;
  Xs[(64 + dpp) * NXP + np] = m;
}

// ---------------------------------------------------------------------------
// Persistent per-batch kernel, fully LDS-resident state. One 87KB region R
// time-shares: z-splits -> G1(f32) -> h-splits -> G2(f32) -> z'(f32) -> z-splits.
// fp32 z lives in registers. Global per step: A-splits (L2-hot) + x + out only.
// ---------------------------------------------------------------------------
__global__ __launch_bounds__(1024) void k_main(
    const float* __restrict__ x_seq, const float* __restrict__ obs_mask,
    const float* __restrict__ W_enc, const float* __restrict__ b_enc,
    const float* __restrict__ ln_g, const float* __restrict__ ln_b,
    const float* __restrict__ W_obs, const float* __restrict__ b_obs,
    const float* __restrict__ W_gate, const float* __restrict__ b_gate,
    const float* __restrict__ W_dec, const float* __restrict__ b_dec,
    const float* __restrict__ W_gc1, const float* __restrict__ W_gc2,
    const float* __restrict__ Wf, const float* __restrict__ bfold,
    const u16* __restrict__ A_hi, const u16* __restrict__ A_md, const u16* __restrict__ A_lo,
    float* __restrict__ out)
{
  const int b = blockIdx.x;
  const int tid = threadIdx.x;
  const int w = tid >> 6, l = tid & 63, lr = l & 15, lg = l >> 4;
  const int dq = tid & 15, nset = tid >> 4;        // epilogue: n = nset+64i, d' = dq*4+c
  const int cr = w & 3, g = w >> 2;                // GEMM wave role

  __shared__ __align__(16) float ldsW1[4096];
  __shared__ __align__(16) float ldsW2[4096];
  __shared__ __align__(16) float ldsWg[4096];
  __shared__ __align__(16) unsigned char ldsR[NP * LDP * 4];   // 87040 B region
  __shared__ float sXv[NP * 4];
  __shared__ float sMask[NP];
  __shared__ float sWo[192], sWfl[192], sWe[192];
  __shared__ float sBe[64], sLng[64], sLnb[64], sWd[64], sBg[64], sBo[64], sBf[64];
  float* ldsG = (float*)ldsR;
  u16*   Xs   = (u16*)ldsR;                        // [2][64][NXP]

  // ---- one-time staging ----
  *(f32x4*)&ldsW1[tid * 4] = *(const f32x4*)&W_gc1[tid * 4];
  *(f32x4*)&ldsW2[tid * 4] = *(const f32x4*)&W_gc2[tid * 4];
  *(f32x4*)&ldsWg[tid * 4] = *(const f32x4*)&W_gate[tid * 4];   // rows 0..63 = Wg_top
  if (tid < 192) { sWo[tid] = W_obs[tid]; sWfl[tid] = Wf[tid]; sWe[tid] = W_enc[tid]; }
  if (tid >= 192 && tid < 256) {
    const int d = tid - 192;
    sBe[d] = b_enc[d]; sLng[d] = ln_g[d]; sLnb[d] = ln_b[d]; sWd[d] = W_dec[d];
    sBg[d] = b_gate[d]; sBo[d] = b_obs[d]; sBf[d] = bfold[d];
  }
  if (tid < NP) {
    const int n = tid;
    sMask[n] = (n < NN) ? obs_mask[b * NN + n] : 0.f;
    float x0 = 0.f, x1 = 0.f, x2 = 0.f;
    if (n < NN) {
      const size_t xo = ((size_t)(b * NN + n) * TT) * 3;
      x0 = x_seq[xo]; x1 = x_seq[xo + 1]; x2 = x_seq[xo + 2];
    }
    sXv[n * 4] = x0; sXv[n * 4 + 1] = x1; sXv[n * 4 + 2] = x2; sXv[n * 4 + 3] = 0.f;
  }
  const float bdec = b_dec[0];
  __syncthreads();

  // ---- init: z0 = x0 @ W_enc + b_enc ; 2-split into Xs ; pred col 0 ----
  float zf[5][4];
#pragma unroll
  for (int i = 0; i < 5; ++i) {
    const int n = nset + 64 * i;
    const bool valid = n < NN;
    const float x0 = sXv[n * 4], x1 = sXv[n * 4 + 1], x2 = sXv[n * 4 + 2];
    float p = 0.f;
#pragma unroll
    for (int c = 0; c < 4; ++c) {
      const int dpp = dq * 4 + c;
      float z = x0 * sWe[dpp] + x1 * sWe[64 + dpp] + x2 * sWe[128 + dpp] + sBe[dpp];
      z = valid ? z : 0.f;
      zf[i][c] = z;
      write_split2(Xs, dpp, n, z);
      p += z * sWd[dpp];
    }
#pragma unroll
    for (int m = 1; m < 16; m <<= 1) p += __shfl_xor(p, m, 64);
    if (dq == 0 && valid) out[(size_t)(b * NN + n) * TT] = p + bdec;
  }
  __syncthreads();

  // ---- 63 scan steps ----
  for (int t = 0; t < 63; ++t) {
    // prefetch x_{t+1} (latency hidden under GEMM-1)
    float px0 = 0.f, px1 = 0.f, px2 = 0.f;
    if (tid < NN) {
      const size_t xo = ((size_t)(b * NN + tid) * TT + (t + 1)) * 3;
      px0 = x_seq[xo]; px1 = x_seq[xo + 1]; px2 = x_seq[xo + 2];
    }

    f32x4 acc[5];
#pragma unroll
    for (int i = 0; i < 5; ++i) acc[i] = (f32x4){0.f, 0.f, 0.f, 0.f};
    gemm_stage(Xs, A_hi, A_md, A_lo, cr, g, lr, lg, acc);   // reads z-splits
    __syncthreads();                                        // B1: Xs reads done
    if (tid < NP) {
      sXv[tid * 4] = px0; sXv[tid * 4 + 1] = px1; sXv[tid * 4 + 2] = px2;
    }
    scatter_G(acc, ldsG, cr, g, lr, lg);                    // G1 fp32 over region
    __syncthreads();                                        // B2

    {   // h1 = tanh(G1 @ W1)  -> 2-split into region
      float o[5][4];
      mat64b(ldsG, ldsW1, nset, dq, o);
      float h1[5][4];
#pragma unroll
      for (int i = 0; i < 5; ++i)
#pragma unroll
        for (int c = 0; c < 4; ++c) h1[i][c] = tanhf(o[i][c]);
      __syncthreads();                                      // B3: G1 reads done
#pragma unroll
      for (int i = 0; i < 5; ++i) {
        const int n = nset + 64 * i;
#pragma unroll
        for (int c = 0; c < 4; ++c) write_split2(Xs, dq * 4 + c, n, h1[i][c]);
      }
    }
    __syncthreads();                                        // B4

#pragma unroll
    for (int i = 0; i < 5; ++i) acc[i] = (f32x4){0.f, 0.f, 0.f, 0.f};
    gemm_stage(Xs, A_hi, A_md, A_lo, cr, g, lr, lg, acc);   // reads h-splits
    __syncthreads();                                        // B5: Xs reads done
    scatter_G(acc, ldsG, cr, g, lr, lg);                    // G2 fp32
    __syncthreads();                                        // B6

    {   // h2 = tanh(G2@W2); LN; z' = 2z+delta; gate; update; pred
      float o[5][4];
      mat64b(ldsG, ldsW2, nset, dq, o);
      float zp[5][4];
      const int nq15 = nset & 15;
#pragma unroll
      for (int i = 0; i < 5; ++i) {
        float h2[4];
#pragma unroll
        for (int c = 0; c < 4; ++c) h2[c] = tanhf(o[i][c]);
        float s = h2[0] + h2[1] + h2[2] + h2[3];
#pragma unroll
        for (int m = 1; m < 16; m <<= 1) s += __shfl_xor(s, m, 64);
        const float mu = s * (1.f / 64.f);
        float q = 0.f;
#pragma unroll
        for (int c = 0; c < 4; ++c) { const float d0 = h2[c] - mu; q += d0 * d0; }
#pragma unroll
        for (int m = 1; m < 16; m <<= 1) q += __shfl_xor(q, m, 64);
        const float rs = rsqrtf(q * (1.f / 64.f) + LNEPS);
#pragma unroll
        for (int c = 0; c < 4; ++c) {
          const int dpp = dq * 4 + c;
          const float delta = (h2[c] - mu) * rs * sLng[dpp] + sLnb[dpp];
          zp[i][c] = 2.f * zf[i][c] + delta;
        }
        // row n only touched by this 16-lane group (same wave): no barrier
        f32x4 zrow = { zp[i][0], zp[i][1], zp[i][2], zp[i][3] };
        *(f32x4*)&ldsG[(nset + 64 * i) * LDP + ((dq ^ nq15) << 2)] = zrow;
      }
      float ps[5][4];
      mat64b(ldsG, ldsWg, nset, dq, ps);
#pragma unroll
      for (int i = 0; i < 5; ++i) {
        const int n = nset + 64 * i;
        const bool valid = n < NN;
        const float x0 = sXv[n * 4], x1 = sXv[n * 4 + 1], x2 = sXv[n * 4 + 2];
        const float mk = sMask[n];
        float p = 0.f;
#pragma unroll
        for (int c = 0; c < 4; ++c) {
          const int dpp = dq * 4 + c;
          const float presig = ps[i][c] + sBg[dpp] + sBf[dpp]
              + x0 * sWfl[dpp] + x1 * sWfl[64 + dpp] + x2 * sWfl[128 + dpp];
          const float gate = 1.f / (1.f + expf(-presig));
          const float zobs = x0 * sWo[dpp] + x1 * sWo[64 + dpp] + x2 * sWo[128 + dpp] + sBo[dpp];
          float zn = zp[i][c] + gate * (zobs - zp[i][c]) * mk;
          zn = valid ? zn : 0.f;
          zf[i][c] = zn;
          p += zn * sWd[dpp];
        }
#pragma unroll
        for (int m = 1; m < 16; m <<= 1) p += __shfl_xor(p, m, 64);
        if (dq == 0 && valid) out[(size_t)(b * NN + n) * TT + (t + 1)] = p + bdec;
      }
      __syncthreads();                                      // B7: z' reads done
#pragma unroll
      for (int i = 0; i < 5; ++i) {
        const int n = nset + 64 * i;
#pragma unroll
        for (int c = 0; c < 4; ++c) write_split2(Xs, dq * 4 + c, n, zf[i][c]);
      }
    }
    __syncthreads();                                        // B8: z-splits ready
  }
}

// ---------------------------------------------------------------------------
extern "C" void kernel_launch(void* const* d_in, const int* in_sizes, int n_in,
                              void* d_out, int out_size, void* d_ws, size_t ws_size,
                              hipStream_t stream) {
  const float* x_seq  = (const float*)d_in[0];
  const float* obs    = (const float*)d_in[1];
  const float* A      = (const float*)d_in[2];
  const float* W_enc  = (const float*)d_in[3];
  const float* b_enc  = (const float*)d_in[4];
  const float* W_gc1  = (const float*)d_in[5];
  const float* W_gc2  = (const float*)d_in[6];
  const float* ln_g   = (const float*)d_in[7];
  const float* ln_b   = (const float*)d_in[8];
  const float* W_obs  = (const float*)d_in[9];
  const float* b_obs  = (const float*)d_in[10];
  const float* W_gate = (const float*)d_in[11];
  const float* b_gate = (const float*)d_in[12];
  const float* W_dec  = (const float*)d_in[13];
  const float* b_dec  = (const float*)d_in[14];
  float* out = (float*)d_out;

  char* p = (char*)d_ws;
  u16* A_hi = (u16*)p; p += (size_t)NP * NP * 2;
  u16* A_md = (u16*)p; p += (size_t)NP * NP * 2;
  u16* A_lo = (u16*)p; p += (size_t)NP * NP * 2;
  float* Wf = (float*)p; p += 256 * 4;
  float* bfold = (float*)p; p += 64 * 4;

  k_prep<<<401, 256, 0, stream>>>(A, W_obs, b_obs, W_gate, A_hi, A_md, A_lo, Wf, bfold);
  k_main<<<NB, 1024, 0, stream>>>(x_seq, obs, W_enc, b_enc, ln_g, ln_b,
                                  W_obs, b_obs, W_gate, b_gate, W_dec, b_dec,
                                  W_gc1, W_gc2, Wf, bfold,
                                  A_hi, A_md, A_lo, out);
  (void)in_sizes; (void)n_in; (void)out_size; (void)ws_size;
}

// Round 7
// 11331.487 us; speedup vs baseline: 5.8558x; 5.8558x over previous
//
#include <hip/hip_runtime.h>

typedef unsigned short u16;
typedef __attribute__((ext_vector_type(8))) short short8;
typedef __attribute__((ext_vector_type(4))) float f32x4;

#define NN 307      // nodes
#define NP 320      // padded nodes
#define TT 64       // time steps
#define NB 64       // batch
#define LDP 68      // ldsG row stride (f32)
#define NXP 328     // Xs (split-state) row stride in u16; 656B, 16B-aligned
#define LNEPS 1e-5f

__device__ __forceinline__ u16 f2bf(float f) {
  union { float f; unsigned u; } v; v.f = f;
  return (u16)((v.u + 0x7FFFu + ((v.u >> 16) & 1u)) >> 16);  // RNE
}
__device__ __forceinline__ float bf2f(u16 h) {
  union { unsigned u; float f; } v; v.u = ((unsigned)h) << 16;
  return v.f;
}
__device__ __forceinline__ void split3(float v, u16 &h, u16 &m, u16 &l) {
  h = f2bf(v);
  float r1 = v - bf2f(h);
  m = f2bf(r1);
  float r2 = r1 - bf2f(m);
  l = f2bf(r2);
}

#define MFMA(a, b, c) __builtin_amdgcn_mfma_f32_16x16x32_bf16((a), (b), (c), 0, 0, 0)

// ---------------------------------------------------------------------------
// prep: A -> 3x bf16 splits (zero-padded 320x320); fold Wf = W_obs @ Wg_bot.
// ---------------------------------------------------------------------------
__global__ __launch_bounds__(256) void k_prep(
    const float* __restrict__ A, const float* __restrict__ W_obs,
    const float* __restrict__ b_obs, const float* __restrict__ W_gate,
    u16* __restrict__ A_hi, u16* __restrict__ A_md, u16* __restrict__ A_lo,
    float* __restrict__ Wf, float* __restrict__ bfold)
{
  if (blockIdx.x < 400) {
    const int e = blockIdx.x * 256 + threadIdx.x;
    const int r = e / NP, c = e - r * NP;
    const float a = (r < NN && c < NN) ? A[r * NN + c] : 0.f;
    u16 h, m, l;
    split3(a, h, m, l);
    A_hi[e] = h; A_md[e] = m; A_lo[e] = l;
  } else if (threadIdx.x < 64) {
    const int dp = threadIdx.x;
    float s0 = 0.f, s1 = 0.f, s2 = 0.f, sb = 0.f;
    for (int d = 0; d < 64; ++d) {
      const float wg = W_gate[(64 + d) * 64 + dp];
      s0 += W_obs[d] * wg;
      s1 += W_obs[64 + d] * wg;
      s2 += W_obs[128 + d] * wg;
      sb += b_obs[d] * wg;
    }
    Wf[dp] = s0; Wf[64 + dp] = s1; Wf[128 + dp] = s2; bfold[dp] = sb;
  }
}

// ---------------------------------------------------------------------------
// GEMM: acc[i] (i<10) += X(64xK from LDS, 2-split) * A(320xK, 3-split)^T
// 8 waves: cr = w&3 picks the 16 X rows, g = w>>2 picks the 160-node half.
// X rows in Xs use k-chunk XOR swizzle: element (r,k) at column k ^ ((r&3)<<3).
// ---------------------------------------------------------------------------
__device__ __forceinline__ void gemm_stage(
    const u16* __restrict__ Xs,
    const u16* __restrict__ Ah, const u16* __restrict__ Am, const u16* __restrict__ Al,
    int cr, int g, int lr, int lg, f32x4 acc[10])
{
  const int r = cr * 16 + lr;
  const int x0off = r * NXP;
  const int x1off = (64 + r) * NXP;
  const int ksw = (lg ^ (r & 3)) << 3;
  unsigned abase[10];
#pragma unroll
  for (int i = 0; i < 10; ++i) abase[i] = (unsigned)((g * 160 + i * 16 + lr) * NP);
  for (int kk = 0; kk < 10; ++kk) {
    const int kc = kk * 32 + ksw;        // swizzled LDS column
    const int ko = kk * 32 + lg * 8;     // linear global column
    const short8 xh = *(const short8*)&Xs[x0off + kc];
    const short8 xm = *(const short8*)&Xs[x1off + kc];
#pragma unroll
    for (int i = 0; i < 10; ++i) {
      const short8 ah = *(const short8*)&Ah[abase[i] + ko];
      const short8 am = *(const short8*)&Am[abase[i] + ko];
      const short8 al = *(const short8*)&Al[abase[i] + ko];
      f32x4 a = acc[i];
      a = MFMA(xh, ah, a);
      a = MFMA(xh, am, a);
      a = MFMA(xm, ah, a);
      a = MFMA(xh, al, a);
      a = MFMA(xm, am, a);
      acc[i] = a;
    }
  }
}

__device__ __forceinline__ void scatter_G(const f32x4 acc[10], float* ldsG,
                                          int cr, int g, int lr, int lg) {
  const int q = cr * 4 + lg;
#pragma unroll
  for (int i = 0; i < 10; ++i) {
    const int n = g * 160 + i * 16 + lr;
    *(f32x4*)&ldsG[n * LDP + ((q ^ (n & 15)) << 2)] = acc[i];
  }
}

// o[i][c] = sum_d ldsG[n_i][d] * ldsW[d][dq*4+c], n_i = nset + 32*i (fp32)
__device__ __forceinline__ void mat64b(const float* __restrict__ ldsG,
                                       const float* __restrict__ ldsW,
                                       int nset, int dq, float o[10][4])
{
#pragma unroll
  for (int i = 0; i < 10; ++i)
#pragma unroll
    for (int c = 0; c < 4; ++c) o[i][c] = 0.f;
  const int nq15 = nset & 15;
  for (int d4 = 0; d4 < 16; ++d4) {
    f32x4 wv[4];
#pragma unroll
    for (int m = 0; m < 4; ++m)
      wv[m] = *(const f32x4*)&ldsW[(d4 * 4 + m) * 64 + dq * 4];
#pragma unroll
    for (int i = 0; i < 10; ++i) {
      const f32x4 gr = *(const f32x4*)&ldsG[(nset + 32 * i) * LDP + ((d4 ^ nq15) << 2)];
#pragma unroll
      for (int m = 0; m < 4; ++m) {
        const float gv = gr[m];
#pragma unroll
        for (int c = 0; c < 4; ++c) o[i][c] += gv * wv[m][c];
      }
    }
  }
}

__device__ __forceinline__ void write_split2(u16* Xs, int dpp, int n, float v) {
  const u16 h = f2bf(v);
  const u16 m = f2bf(v - bf2f(h));
  const int np = n ^ ((dpp & 3) << 3);   // matches gemm read swizzle
  Xs[dpp * NXP + np] = h;
  Xs[(64 + dpp) * NXP + np] = m;
}

// ---------------------------------------------------------------------------
// Persistent per-batch kernel, fully LDS-resident state, 512 threads (the
// 128-VGPR no-spill regime round 2 validated; 1024 threads forced a 64-VGPR
// cap and catastrophic scratch spills in round 3).
// One 87KB region time-shares: z-splits -> G1(f32) -> h-splits -> G2(f32)
// -> z'(f32) -> z-splits. fp32 z lives in registers.
// ---------------------------------------------------------------------------
__global__ __launch_bounds__(512, 1) void k_main(
    const float* __restrict__ x_seq, const float* __restrict__ obs_mask,
    const float* __restrict__ W_enc, const float* __restrict__ b_enc,
    const float* __restrict__ ln_g, const float* __restrict__ ln_b,
    const float* __restrict__ W_obs, const float* __restrict__ b_obs,
    const float* __restrict__ W_gate, const float* __restrict__ b_gate,
    const float* __restrict__ W_dec, const float* __restrict__ b_dec,
    const float* __restrict__ W_gc1, const float* __restrict__ W_gc2,
    const float* __restrict__ Wf, const float* __restrict__ bfold,
    const u16* __restrict__ A_hi, const u16* __restrict__ A_md, const u16* __restrict__ A_lo,
    float* __restrict__ out)
{
  const int b = blockIdx.x;
  const int tid = threadIdx.x;
  const int w = tid >> 6, l = tid & 63, lr = l & 15, lg = l >> 4;
  const int dq = tid & 15, nset = tid >> 4;        // epilogue: n = nset+32i, d' = dq*4+c
  const int cr = w & 3, g = w >> 2;                // GEMM wave role

  __shared__ __align__(16) float ldsW1[4096];
  __shared__ __align__(16) float ldsW2[4096];
  __shared__ __align__(16) float ldsWg[4096];
  __shared__ __align__(16) unsigned char ldsR[NP * LDP * 4];   // 87040 B region
  __shared__ float sXv[NP * 4];
  __shared__ float sMask[NP];
  __shared__ float sWo[192], sWfl[192], sWe[192];
  __shared__ float sBe[64], sLng[64], sLnb[64], sWd[64], sBg[64], sBo[64], sBf[64];
  float* ldsG = (float*)ldsR;
  u16*   Xs   = (u16*)ldsR;                        // [2][64][NXP]

  // ---- one-time staging ----
  *(f32x4*)&ldsW1[tid * 8]     = *(const f32x4*)&W_gc1[tid * 8];
  *(f32x4*)&ldsW1[tid * 8 + 4] = *(const f32x4*)&W_gc1[tid * 8 + 4];
  *(f32x4*)&ldsW2[tid * 8]     = *(const f32x4*)&W_gc2[tid * 8];
  *(f32x4*)&ldsW2[tid * 8 + 4] = *(const f32x4*)&W_gc2[tid * 8 + 4];
  *(f32x4*)&ldsWg[tid * 8]     = *(const f32x4*)&W_gate[tid * 8];      // rows 0..63
  *(f32x4*)&ldsWg[tid * 8 + 4] = *(const f32x4*)&W_gate[tid * 8 + 4];
  if (tid < 192) { sWo[tid] = W_obs[tid]; sWfl[tid] = Wf[tid]; sWe[tid] = W_enc[tid]; }
  if (tid >= 192 && tid < 256) {
    const int d = tid - 192;
    sBe[d] = b_enc[d]; sLng[d] = ln_g[d]; sLnb[d] = ln_b[d]; sWd[d] = W_dec[d];
    sBg[d] = b_gate[d]; sBo[d] = b_obs[d]; sBf[d] = bfold[d];
  }
  if (tid < NP) {
    const int n = tid;
    sMask[n] = (n < NN) ? obs_mask[b * NN + n] : 0.f;
    float x0 = 0.f, x1 = 0.f, x2 = 0.f;
    if (n < NN) {
      const size_t xo = ((size_t)(b * NN + n) * TT) * 3;
      x0 = x_seq[xo]; x1 = x_seq[xo + 1]; x2 = x_seq[xo + 2];
    }
    sXv[n * 4] = x0; sXv[n * 4 + 1] = x1; sXv[n * 4 + 2] = x2; sXv[n * 4 + 3] = 0.f;
  }
  const float bdec = b_dec[0];
  __syncthreads();

  // ---- init: z0 = x0 @ W_enc + b_enc ; 2-split into Xs ; pred col 0 ----
  float zf[10][4];
#pragma unroll
  for (int i = 0; i < 10; ++i) {
    const int n = nset + 32 * i;
    const bool valid = n < NN;
    const float x0 = sXv[n * 4], x1 = sXv[n * 4 + 1], x2 = sXv[n * 4 + 2];
    float p = 0.f;
#pragma unroll
    for (int c = 0; c < 4; ++c) {
      const int dpp = dq * 4 + c;
      float z = x0 * sWe[dpp] + x1 * sWe[64 + dpp] + x2 * sWe[128 + dpp] + sBe[dpp];
      z = valid ? z : 0.f;
      zf[i][c] = z;
      write_split2(Xs, dpp, n, z);
      p += z * sWd[dpp];
    }
#pragma unroll
    for (int m = 1; m < 16; m <<= 1) p += __shfl_xor(p, m, 64);
    if (dq == 0 && valid) out[(size_t)(b * NN + n) * TT] = p + bdec;
  }
  __syncthreads();

  // ---- 63 scan steps ----
  for (int t = 0; t < 63; ++t) {
    // prefetch x_{t+1} (latency hidden under GEMM-1)
    float px0 = 0.f, px1 = 0.f, px2 = 0.f;
    if (tid < NN) {
      const size_t xo = ((size_t)(b * NN + tid) * TT + (t + 1)) * 3;
      px0 = x_seq[xo]; px1 = x_seq[xo + 1]; px2 = x_seq[xo + 2];
    }

    f32x4 acc[10];
#pragma unroll
    for (int i = 0; i < 10; ++i) acc[i] = (f32x4){0.f, 0.f, 0.f, 0.f};
    gemm_stage(Xs, A_hi, A_md, A_lo, cr, g, lr, lg, acc);   // reads z-splits
    __syncthreads();                                        // B1: Xs reads done
    if (tid < NP) {
      sXv[tid * 4] = px0; sXv[tid * 4 + 1] = px1; sXv[tid * 4 + 2] = px2;
    }
    scatter_G(acc, ldsG, cr, g, lr, lg);                    // G1 fp32 over region
    __syncthreads();                                        // B2

    {   // h1 = tanh(G1 @ W1)  -> 2-split into region
      float o[10][4];
      mat64b(ldsG, ldsW1, nset, dq, o);
#pragma unroll
      for (int i = 0; i < 10; ++i)
#pragma unroll
        for (int c = 0; c < 4; ++c) o[i][c] = tanhf(o[i][c]);
      __syncthreads();                                      // B3: G1 reads done
#pragma unroll
      for (int i = 0; i < 10; ++i) {
        const int n = nset + 32 * i;
#pragma unroll
        for (int c = 0; c < 4; ++c) write_split2(Xs, dq * 4 + c, n, o[i][c]);
      }
    }
    __syncthreads();                                        // B4

#pragma unroll
    for (int i = 0; i < 10; ++i) acc[i] = (f32x4){0.f, 0.f, 0.f, 0.f};
    gemm_stage(Xs, A_hi, A_md, A_lo, cr, g, lr, lg, acc);   // reads h-splits
    __syncthreads();                                        // B5: Xs reads done
    scatter_G(acc, ldsG, cr, g, lr, lg);                    // G2 fp32
    __syncthreads();                                        // B6

    {   // h2 = tanh(G2@W2); LN; z' = 2z+delta; gate; update; pred
      float o[10][4];
      mat64b(ldsG, ldsW2, nset, dq, o);
      float zp[10][4];
      const int nq15 = nset & 15;
#pragma unroll
      for (int i = 0; i < 10; ++i) {
        float h2[4];
#pragma unroll
        for (int c = 0; c < 4; ++c) h2[c] = tanhf(o[i][c]);
        float s = h2[0] + h2[1] + h2[2] + h2[3];
#pragma unroll
        for (int m = 1; m < 16; m <<= 1) s += __shfl_xor(s, m, 64);
        const float mu = s * (1.f / 64.f);
        float q = 0.f;
#pragma unroll
        for (int c = 0; c < 4; ++c) { const float d0 = h2[c] - mu; q += d0 * d0; }
#pragma unroll
        for (int m = 1; m < 16; m <<= 1) q += __shfl_xor(q, m, 64);
        const float rs = rsqrtf(q * (1.f / 64.f) + LNEPS);
#pragma unroll
        for (int c = 0; c < 4; ++c) {
          const int dpp = dq * 4 + c;
          const float delta = (h2[c] - mu) * rs * sLng[dpp] + sLnb[dpp];
          zp[i][c] = 2.f * zf[i][c] + delta;
        }
        // row n only touched by this 16-lane group (same wave): no barrier
        f32x4 zrow = { zp[i][0], zp[i][1], zp[i][2], zp[i][3] };
        *(f32x4*)&ldsG[(nset + 32 * i) * LDP + ((dq ^ nq15) << 2)] = zrow;
      }
      float ps[10][4];
      mat64b(ldsG, ldsWg, nset, dq, ps);
#pragma unroll
      for (int i = 0; i < 10; ++i) {
        const int n = nset + 32 * i;
        const bool valid = n < NN;
        const float x0 = sXv[n * 4], x1 = sXv[n * 4 + 1], x2 = sXv[n * 4 + 2];
        const float mk = sMask[n];
        float p = 0.f;
#pragma unroll
        for (int c = 0; c < 4; ++c) {
          const int dpp = dq * 4 + c;
          const float presig = ps[i][c] + sBg[dpp] + sBf[dpp]
              + x0 * sWfl[dpp] + x1 * sWfl[64 + dpp] + x2 * sWfl[128 + dpp];
          const float gate = 1.f / (1.f + expf(-presig));
          const float zobs = x0 * sWo[dpp] + x1 * sWo[64 + dpp] + x2 * sWo[128 + dpp] + sBo[dpp];
          float zn = zp[i][c] + gate * (zobs - zp[i][c]) * mk;
          zn = valid ? zn : 0.f;
          zf[i][c] = zn;
          p += zn * sWd[dpp];
        }
#pragma unroll
        for (int m = 1; m < 16; m <<= 1) p += __shfl_xor(p, m, 64);
        if (dq == 0 && valid) out[(size_t)(b * NN + n) * TT + (t + 1)] = p + bdec;
      }
      __syncthreads();                                      // B7: z' reads done
#pragma unroll
      for (int i = 0; i < 10; ++i) {
        const int n = nset + 32 * i;
#pragma unroll
        for (int c = 0; c < 4; ++c) write_split2(Xs, dq * 4 + c, n, zf[i][c]);
      }
    }
    __syncthreads();                                        // B8: z-splits ready
  }
}

// ---------------------------------------------------------------------------
extern "C" void kernel_launch(void* const* d_in, const int* in_sizes, int n_in,
                              void* d_out, int out_size, void* d_ws, size_t ws_size,
                              hipStream_t stream) {
  const float* x_seq  = (const float*)d_in[0];
  const float* obs    = (const float*)d_in[1];
  const float* A      = (const float*)d_in[2];
  const float* W_enc  = (const float*)d_in[3];
  const float* b_enc  = (const float*)d_in[4];
  const float* W_gc1  = (const float*)d_in[5];
  const float* W_gc2  = (const float*)d_in[6];
  const float* ln_g   = (const float*)d_in[7];
  const float* ln_b   = (const float*)d_in[8];
  const float* W_obs  = (const float*)d_in[9];
  const float* b_obs  = (const float*)d_in[10];
  const float* W_gate = (const float*)d_in[11];
  const float* b_gate = (const float*)d_in[12];
  const float* W_dec  = (const float*)d_in[13];
  const float* b_dec  = (const float*)d_in[14];
  float* out = (float*)d_out;

  char* p = (char*)d_ws;
  u16* A_hi = (u16*)p; p += (size_t)NP * NP * 2;
  u16* A_md = (u16*)p; p += (size_t)NP * NP * 2;
  u16* A_lo = (u16*)p; p += (size_t)NP * NP * 2;
  float* Wf = (float*)p; p += 256 * 4;
  float* bfold = (float*)p; p += 64 * 4;

  k_prep<<<401, 256, 0, stream>>>(A, W_obs, b_obs, W_gate, A_hi, A_md, A_lo, Wf, bfold);
  k_main<<<NB, 512, 0, stream>>>(x_seq, obs, W_enc, b_enc, ln_g, ln_b,
                                 W_obs, b_obs, W_gate, b_gate, W_dec, b_dec,
                                 W_gc1, W_gc2, Wf, bfold,
                                 A_hi, A_md, A_lo, out);
  (void)in_sizes; (void)n_in; (void)out_size; (void)ws_size;
}